// Round 2
// baseline (1711.956 us; speedup 1.0000x reference)
//
#include <hip/hip_runtime.h>
#include <math.h>

#define N_ROWS 65536
#define CB 1024

// ---------------------------------------------------------------------------
// Exact emulation of numpy's pairwise_sum for n=64 fp32 (AVX-512 path):
// lane sums (x[l]+x[l+16])+(x[l+32]+x[l+48]), then reduce tree at distance
// 8,4,2,1. fp contract OFF so squares are not fused into adds (hipcc default
// -ffp-contract=fast would change rounding vs numpy).  VERIFIED absmax=0 (R1).
// ---------------------------------------------------------------------------
__device__ __forceinline__ float tree_sum64_sq(const float* x) {
#pragma clang fp contract(off)
    float sq[64];
#pragma unroll
    for (int i = 0; i < 64; ++i) sq[i] = x[i] * x[i];
    float s[16];
#pragma unroll
    for (int l = 0; l < 16; ++l) s[l] = (sq[l] + sq[l + 16]) + (sq[l + 32] + sq[l + 48]);
    float t[8];
#pragma unroll
    for (int l = 0; l < 8; ++l) t[l] = s[l] + s[l + 8];
    float u[4];
#pragma unroll
    for (int l = 0; l < 4; ++l) u[l] = t[l] + t[l + 4];
    float v0 = u[0] + u[2];
    float v1 = u[1] + u[3];
    return v0 + v1;
}

// sorted-triple insert, strict < (ties keep earlier-inserted = lower index;
// feeding ascending j preserves lax.top_k tie-breaking).  VERIFIED (R1).
__device__ __forceinline__ void top3_insert(float d, int j,
                                            float& v0, float& v1, float& v2,
                                            int& i0, int& i1, int& i2) {
    bool b0 = d < v0, b1 = d < v1, b2 = d < v2;
    v2 = b1 ? v1 : (b2 ? d : v2);
    i2 = b1 ? i1 : (b2 ? j : i2);
    v1 = b0 ? v0 : (b1 ? d : v1);
    i1 = b0 ? i0 : (b1 ? j : i1);
    v0 = b0 ? d : v0;
    i0 = b0 ? j : i0;
}

// B[j] = np.sum(emb[j]**2)  (exact tree emulation)
__global__ __launch_bounds__(256) void embB_kernel(const float* __restrict__ emb,
                                                   float* __restrict__ B) {
    int j = blockIdx.x * 256 + threadIdx.x;
    if (j >= CB) return;
    float e[64];
    const float4* e4 = (const float4*)(emb + (size_t)j * 64);
#pragma unroll
    for (int k = 0; k < 16; ++k) {
        float4 v = e4[k];
        e[4 * k] = v.x; e[4 * k + 1] = v.y; e[4 * k + 2] = v.z; e[4 * k + 3] = v.w;
    }
    B[j] = tree_sum64_sq(e);
}

// ---------------------------------------------------------------------------
// Fused: scoring + encodings zero-fill (interleaved; overlaps HBM writes with
// VALU FMAs) + top3 + one-hot ones + z_q_st + idx + hist/loss atomics.
// One block = 256 threads = 256 z-rows; each thread scans all 1024 codebook
// entries with 4 independent FMA chains (ILP to hide the 4-cyc dep latency
// at 1 wave/SIMD occupancy). Exact per-j math: strict ascending-k fmaf chain,
// d = (A+Bj) - 2*acc (fma-contraction of the final sub is bit-identical since
// 2*acc is exact).
// ---------------------------------------------------------------------------
__global__ __launch_bounds__(256) void mega_kernel(const float* __restrict__ z,
                                                   const float* __restrict__ emb,
                                                   const float* __restrict__ B,
                                                   float* __restrict__ out0,
                                                   float* __restrict__ out3,
                                                   float* __restrict__ out4,
                                                   int* __restrict__ hist,
                                                   float* __restrict__ lossAcc) {
    const int t = threadIdx.x;
    const int row = blockIdx.x * 256 + t;

    float zr[64];
    const float4* z4 = (const float4*)(z + (size_t)row * 64);
#pragma unroll
    for (int k = 0; k < 16; ++k) {
        float4 v = z4[k];
        zr[4 * k] = v.x; zr[4 * k + 1] = v.y; zr[4 * k + 2] = v.z; zr[4 * k + 3] = v.w;
    }
    float A = tree_sum64_sq(zr);

    // this block's slice of the encodings output: 256 rows * 3*1024 floats
    // = 196608 float4. Coalesced zero stores interleaved into the j-loop:
    // 3 per group of 4 codebook entries (256 groups * 3 = 768 per thread).
    float4* zb = (float4*)out3 + (size_t)blockIdx.x * 196608;
    const float4 zero4 = make_float4(0.0f, 0.0f, 0.0f, 0.0f);

    float v0 = 3.402823466e38f, v1 = 3.402823466e38f, v2 = 3.402823466e38f;
    int i0 = 0, i1 = 0, i2 = 0;

    for (int g = 0; g < 256; ++g) {
        // interleaved zero-fill (fire-and-forget; drains during FMA work)
        zb[(size_t)(3 * g + 0) * 256 + t] = zero4;
        zb[(size_t)(3 * g + 1) * 256 + t] = zero4;
        zb[(size_t)(3 * g + 2) * 256 + t] = zero4;

        const int j = 4 * g;                           // wave-uniform
        const float4* e0p = (const float4*)(emb + (size_t)(j + 0) * 64);
        const float4* e1p = (const float4*)(emb + (size_t)(j + 1) * 64);
        const float4* e2p = (const float4*)(emb + (size_t)(j + 2) * 64);
        const float4* e3p = (const float4*)(emb + (size_t)(j + 3) * 64);
        float b0 = B[j], b1 = B[j + 1], b2 = B[j + 2], b3 = B[j + 3];

        float a0 = 0.0f, a1 = 0.0f, a2 = 0.0f, a3 = 0.0f;
#pragma unroll
        for (int k = 0; k < 16; ++k) {
            float4 e0 = e0p[k], e1 = e1p[k], e2 = e2p[k], e3 = e3p[k];
            float x0 = zr[4 * k], x1 = zr[4 * k + 1], x2 = zr[4 * k + 2], x3 = zr[4 * k + 3];
            a0 = fmaf(x0, e0.x, a0); a0 = fmaf(x1, e0.y, a0);
            a0 = fmaf(x2, e0.z, a0); a0 = fmaf(x3, e0.w, a0);
            a1 = fmaf(x0, e1.x, a1); a1 = fmaf(x1, e1.y, a1);
            a1 = fmaf(x2, e1.z, a1); a1 = fmaf(x3, e1.w, a1);
            a2 = fmaf(x0, e2.x, a2); a2 = fmaf(x1, e2.y, a2);
            a2 = fmaf(x2, e2.z, a2); a2 = fmaf(x3, e2.w, a2);
            a3 = fmaf(x0, e3.x, a3); a3 = fmaf(x1, e3.y, a3);
            a3 = fmaf(x2, e3.z, a3); a3 = fmaf(x3, e3.w, a3);
        }
        float d0 = (A + b0) - 2.0f * a0;
        float d1 = (A + b1) - 2.0f * a1;
        float d2 = (A + b2) - 2.0f * a2;
        float d3 = (A + b3) - 2.0f * a3;
        // ascending-j insertion preserves exact tie-break semantics
        top3_insert(d0, j + 0, v0, v1, v2, i0, i1, i2);
        top3_insert(d1, j + 1, v0, v1, v2, i0, i1, i2);
        top3_insert(d2, j + 2, v0, v1, v2, i0, i1, i2);
        top3_insert(d3, j + 3, v0, v1, v2, i0, i1, i2);
    }

    // barrier drains vmcnt(0): all zero stores of this block's slice are
    // complete before any thread overwrites its ones (block-local hazard only)
    __syncthreads();

    size_t rb = (size_t)row * 3072;
    out3[rb + i0]          = 1.0f;
    out3[rb + 1024 + i1]   = 1.0f;
    out3[rb + 2048 + i2]   = 1.0f;

    // epilogue: z_q_st, loss, idx, hist
    const float* e0 = emb + (size_t)i0 * 64;
    const float* e1 = emb + (size_t)i1 * 64;
    const float* e2 = emb + (size_t)i2 * 64;
    float4* o4 = (float4*)(out0 + (size_t)row * 64);

    float lsum = 0.0f;
#pragma unroll
    for (int k4 = 0; k4 < 16; ++k4) {
        float4 st;
        {
            int k = 4 * k4;
            float zq = ((e0[k] + e1[k]) + e2[k]) / 3.0f;
            float df = zq - zr[k];
            st.x = zr[k] + df;
            lsum = fmaf(df, df, lsum);
        }
        {
            int k = 4 * k4 + 1;
            float zq = ((e0[k] + e1[k]) + e2[k]) / 3.0f;
            float df = zq - zr[k];
            st.y = zr[k] + df;
            lsum = fmaf(df, df, lsum);
        }
        {
            int k = 4 * k4 + 2;
            float zq = ((e0[k] + e1[k]) + e2[k]) / 3.0f;
            float df = zq - zr[k];
            st.z = zr[k] + df;
            lsum = fmaf(df, df, lsum);
        }
        {
            int k = 4 * k4 + 3;
            float zq = ((e0[k] + e1[k]) + e2[k]) / 3.0f;
            float df = zq - zr[k];
            st.w = zr[k] + df;
            lsum = fmaf(df, df, lsum);
        }
        o4[k4] = st;
    }

    size_t ob = (size_t)row * 3;
    out4[ob]     = (float)i0;
    out4[ob + 1] = (float)i1;
    out4[ob + 2] = (float)i2;
    atomicAdd(&hist[i0], 1);
    atomicAdd(&hist[i1], 1);
    atomicAdd(&hist[i2], 1);

    // wave-level reduce of loss partial, one atomic per wave
#pragma unroll
    for (int off = 32; off >= 1; off >>= 1) lsum += __shfl_down(lsum, off);
    if ((t & 63) == 0) atomicAdd(lossAcc, lsum);
}

// Perplexity from histogram + loss finalize.
__global__ __launch_bounds__(256) void finalize_kernel(const int* __restrict__ hist,
                                                       const float* __restrict__ lossAcc,
                                                       float* __restrict__ out1,
                                                       float* __restrict__ out2) {
    __shared__ float red[256];
    int t = threadIdx.x;
    float local = 0.0f;
    for (int b = t; b < CB; b += 256) {
        float em = (float)hist[b] / 196608.0f;
        local += em * logf(em + 1e-10f);
    }
    red[t] = local;
    __syncthreads();
    for (int s = 128; s >= 1; s >>= 1) {
        if (t < s) red[t] += red[t + s];
        __syncthreads();
    }
    if (t == 0) {
        *out2 = expf(-red[0]);
        float m = *lossAcc / 4194304.0f;
        *out1 = 0.25f * m + m;   // BETA_C*mse + mse (stop_gradient = id fwd)
    }
}

extern "C" void kernel_launch(void* const* d_in, const int* in_sizes, int n_in,
                              void* d_out, int out_size, void* d_ws, size_t ws_size,
                              hipStream_t stream) {
    const float* z   = (const float*)d_in[0];   // [16,64,64,64] -> 65536 x 64
    const float* emb = (const float*)d_in[1];   // [1024, 64]

    float* out  = (float*)d_out;
    float* out0 = out;                                    // z_q_st     4194304
    float* out1 = out + 4194304;                          // loss       1
    float* out2 = out + 4194305;                          // perplexity 1
    float* out3 = out + 4194306;                          // encodings  201326592
    float* out4 = out + 4194306 + 201326592ll;            // topk_idx   196608

    int*   hist    = (int*)d_ws;                          // 1024 ints @ 0
    float* lossAcc = (float*)((char*)d_ws + 4096);        // 1 float
    float* B       = (float*)((char*)d_ws + 8192);        // 1024 floats

    hipMemsetAsync(d_ws, 0, 4096 + 16, stream);           // hist + lossAcc

    embB_kernel<<<4, 256, 0, stream>>>(emb, B);
    mega_kernel<<<N_ROWS / 256, 256, 0, stream>>>(z, emb, B, out0, out3, out4,
                                                  hist, lossAcc);
    finalize_kernel<<<1, 256, 0, stream>>>(hist, lossAcc, out1, out2);
}